// Round 3
// baseline (709.413 us; speedup 1.0000x reference)
//
#include <hip/hip_runtime.h>

#define NN 512
#define DD 64
#define BB 64
#define ND (NN * DD)          // 32768

typedef __bf16 bf16x8 __attribute__((ext_vector_type(8)));
typedef float  f32x4  __attribute__((ext_vector_type(4)));

// fp32 -> bf16 round-to-nearest-even
__device__ __forceinline__ unsigned short f2bf(float x) {
    unsigned int u = __float_as_uint(x);
    unsigned int r = u + 0x7fffu + ((u >> 16) & 1u);
    return (unsigned short)(r >> 16);
}
__device__ __forceinline__ float bf2f(unsigned short u) {
    return __uint_as_float(((unsigned int)u) << 16);
}
// split float4 into hi/lo bf16 pairs
__device__ __forceinline__ void cvt4(const float4& x, ushort4& h, ushort4& l) {
    float xs[4] = {x.x, x.y, x.z, x.w};
    unsigned short hh[4], ll[4];
#pragma unroll
    for (int i = 0; i < 4; ++i) {
        hh[i] = f2bf(xs[i]);
        ll[i] = f2bf(xs[i] - bf2f(hh[i]));
    }
    h = make_ushort4(hh[0], hh[1], hh[2], hh[3]);
    l = make_ushort4(ll[0], ll[1], ll[2], ll[3]);
}
__device__ __forceinline__ bf16x8 ld_bf8(const unsigned short* p) {
    int4 v = *reinterpret_cast<const int4*>(p);
    return __builtin_bit_cast(bf16x8, v);
}
__device__ __forceinline__ f32x4 mfma16(bf16x8 a, bf16x8 b, f32x4 c) {
    return __builtin_amdgcn_mfma_f32_16x16x32_bf16(a, b, c, 0, 0, 0);
}

// ---------------------------------------------------------------------------
// MFMA GEMM v3.
//   out[b,z,i,f] = alpha * sum_k A[b,i,k]*B[(b,z),f,k] (+beta*Vm) (+Zt) (+bias)
// AMODE 0: A fp32 row-major (lda), cvt-staged hi/lo to LDS, dbuf, 1 barrier/step.
// AMODE 1: A hi/lo bf16 planes row-major (lda), register-direct (no LDS).
// B: always hi/lo bf16 planes, layout [.,f,kdim], register-direct.
// Vm/Zt: hi/lo planes col-major [b][64 f][512 n] (batch stride ND).
// OUTF 0: hi/lo col-major planes. 1: fp32 col-major. 2: hi/lo row-major [n][64].
// 3-term MFMA (ah*bh + ah*bl + al*bh): ~fp32 precision.
// ---------------------------------------------------------------------------
template <int AMODE, bool HAS_VM, bool HAS_Z, bool HAS_BIAS, int OUTF>
__global__ __launch_bounds__(256) void gemm_v3(
    const float* __restrict__ Afp,
    const unsigned short* __restrict__ Ah, const unsigned short* __restrict__ Al,
    int lda, long aBatch,
    const unsigned short* __restrict__ Bh, const unsigned short* __restrict__ Bl,
    long bBatch, long bZ,
    const unsigned short* __restrict__ Vmh, const unsigned short* __restrict__ Vml,
    const unsigned short* __restrict__ Zth, const unsigned short* __restrict__ Ztl,
    const float* __restrict__ bias, float alpha, float beta, int kdim,
    unsigned short* __restrict__ outH, unsigned short* __restrict__ outL,
    float* __restrict__ outF, long outZ)
{
    const int b = blockIdx.y, z = blockIdx.z;
    const int i0 = blockIdx.x * 64;
    const long aOff = (long)b * aBatch;
    const long bOff = (long)b * bBatch + (long)z * bZ;

    __shared__ __align__(16) unsigned short sAh[(AMODE == 0) ? 8192 : 8];
    __shared__ __align__(16) unsigned short sAl[(AMODE == 0) ? 8192 : 8];

    const int t = threadIdx.x;
    const int w = t >> 6, lane = t & 63;
    const int wr = w >> 1, wc = w & 1;
    const int lr = lane & 15, lg = lane >> 4;

    f32x4 acc[2][2];
#pragma unroll
    for (int m = 0; m < 2; ++m)
#pragma unroll
        for (int n = 0; n < 2; ++n) acc[m][n] = f32x4{0.f, 0.f, 0.f, 0.f};

    const int steps = kdim >> 6;
    float4 ra[4];
    if (AMODE == 0) {
#pragma unroll
        for (int l = 0; l < 4; ++l) {
            int q = t + l * 256, r = q >> 4, c = q & 15;
            ra[l] = *reinterpret_cast<const float4*>(Afp + aOff + (long)(i0 + r) * lda + c * 4);
        }
    }

    for (int s = 0; s < steps; ++s) {
        const int k0 = s << 6;
        int p = 0;
        if (AMODE == 0) {
            p = (s & 1) << 12;   // 4096-short buffer select
#pragma unroll
            for (int l = 0; l < 4; ++l) {
                int q = t + l * 256, r = q >> 4, c = q & 15;
                int idx = p + r * 64 + (((c >> 1) ^ (r & 7)) << 3) + ((c & 1) << 2);
                ushort4 h4, l4;
                cvt4(ra[l], h4, l4);
                *reinterpret_cast<ushort4*>(&sAh[idx]) = h4;
                *reinterpret_cast<ushort4*>(&sAl[idx]) = l4;
            }
            __syncthreads();
            if (s + 1 < steps) {
#pragma unroll
                for (int l = 0; l < 4; ++l) {
                    int q = t + l * 256, r = q >> 4, c = q & 15;
                    ra[l] = *reinterpret_cast<const float4*>(
                        Afp + aOff + (long)(i0 + r) * lda + (k0 + 64) + c * 4);
                }
            }
        }
#pragma unroll
        for (int c2 = 0; c2 < 2; ++c2) {
            const int oct = c2 * 4 + lg;
            bf16x8 a_h[2], a_l[2], b_h[2], b_l[2];
#pragma unroll
            for (int m = 0; m < 2; ++m) {
                if (AMODE == 0) {
                    int row = wr * 32 + m * 16 + lr;
                    int lidx = p + row * 64 + (((oct) ^ (row & 7)) << 3);
                    a_h[m] = ld_bf8(&sAh[lidx]);
                    a_l[m] = ld_bf8(&sAl[lidx]);
                } else {
                    long ga = aOff + (long)(i0 + wr * 32 + m * 16 + lr) * lda + k0 + oct * 8;
                    a_h[m] = ld_bf8(Ah + ga);
                    a_l[m] = ld_bf8(Al + ga);
                }
                long gb = bOff + (long)(wc * 32 + m * 16 + lr) * kdim + k0 + oct * 8;
                b_h[m] = ld_bf8(Bh + gb);
                b_l[m] = ld_bf8(Bl + gb);
            }
#pragma unroll
            for (int m = 0; m < 2; ++m)
#pragma unroll
                for (int n = 0; n < 2; ++n) {
                    acc[m][n] = mfma16(a_h[m], b_h[n], acc[m][n]);
                    acc[m][n] = mfma16(a_h[m], b_l[n], acc[m][n]);
                    acc[m][n] = mfma16(a_l[m], b_h[n], acc[m][n]);
                }
        }
    }

    // epilogue: C/D frag: col = lane&15, row = (lane>>4)*4 + reg (verified)
    const long cOff = (long)b * ND;                 // col-major [64 f][512 n]
    const long oOff = (long)z * outZ + cOff;
#pragma unroll
    for (int m = 0; m < 2; ++m) {
        const int nb = i0 + wr * 32 + m * 16 + lg * 4;
#pragma unroll
        for (int n = 0; n < 2; ++n) {
            const int f = wc * 32 + n * 16 + lr;
            float4 v;
            v.x = alpha * acc[m][n][0]; v.y = alpha * acc[m][n][1];
            v.z = alpha * acc[m][n][2]; v.w = alpha * acc[m][n][3];
            if (HAS_VM) {
                long a2 = cOff + (long)f * NN + nb;
                ushort4 mh = *reinterpret_cast<const ushort4*>(Vmh + a2);
                ushort4 ml = *reinterpret_cast<const ushort4*>(Vml + a2);
                v.x += beta * (bf2f(mh.x) + bf2f(ml.x));
                v.y += beta * (bf2f(mh.y) + bf2f(ml.y));
                v.z += beta * (bf2f(mh.z) + bf2f(ml.z));
                v.w += beta * (bf2f(mh.w) + bf2f(ml.w));
            }
            if (HAS_Z) {
                long a2 = cOff + (long)f * NN + nb;
                ushort4 zh = *reinterpret_cast<const ushort4*>(Zth + a2);
                ushort4 zl = *reinterpret_cast<const ushort4*>(Ztl + a2);
                v.x += bf2f(zh.x) + bf2f(zl.x);
                v.y += bf2f(zh.y) + bf2f(zl.y);
                v.z += bf2f(zh.z) + bf2f(zl.z);
                v.w += bf2f(zh.w) + bf2f(zl.w);
            }
            if (HAS_BIAS) {
                float bf = bias[f];
                v.x += bf; v.y += bf; v.z += bf; v.w += bf;
            }
            if (OUTF == 0) {
                ushort4 h4, l4;
                cvt4(v, h4, l4);
                *reinterpret_cast<ushort4*>(outH + oOff + (long)f * NN + nb) = h4;
                *reinterpret_cast<ushort4*>(outL + oOff + (long)f * NN + nb) = l4;
            } else if (OUTF == 1) {
                *reinterpret_cast<float4*>(outF + cOff + (long)f * NN + nb) = v;
            } else {
                float vs[4] = {v.x, v.y, v.z, v.w};
#pragma unroll
                for (int jj = 0; jj < 4; ++jj) {
                    unsigned short hi = f2bf(vs[jj]);
                    outH[cOff + (long)(nb + jj) * DD + f] = hi;
                    outL[cOff + (long)(nb + jj) * DD + f] = f2bf(vs[jj] - bf2f(hi));
                }
            }
        }
    }
}

// ---------------------------------------------------------------------------
// AE[b,i,j] = relu(dot(X0[b,i,:], X0[b,j,:])), diag zeroed.
// X0 hi/lo bf16 planes row-major [512][64]. Register-direct, no LDS.
// ---------------------------------------------------------------------------
__global__ __launch_bounds__(256) void outer_v3(
    const unsigned short* __restrict__ X0h, const unsigned short* __restrict__ X0l,
    float* __restrict__ AE)
{
    const int b = blockIdx.z;
    const int j0 = blockIdx.x * 64, i0 = blockIdx.y * 64;
    const long xb = (long)b * ND;

    const int t = threadIdx.x;
    const int w = t >> 6, lane = t & 63;
    const int wr = w >> 1, wc = w & 1;
    const int lr = lane & 15, lg = lane >> 4;

    f32x4 acc[2][2];
#pragma unroll
    for (int m = 0; m < 2; ++m)
#pragma unroll
        for (int n = 0; n < 2; ++n) acc[m][n] = f32x4{0.f, 0.f, 0.f, 0.f};

#pragma unroll
    for (int c2 = 0; c2 < 2; ++c2) {
        const int oct = c2 * 4 + lg;
        bf16x8 a_h[2], a_l[2], b_h[2], b_l[2];
#pragma unroll
        for (int m = 0; m < 2; ++m) {
            long ga = xb + (long)(i0 + wr * 32 + m * 16 + lr) * DD + oct * 8;
            a_h[m] = ld_bf8(X0h + ga);
            a_l[m] = ld_bf8(X0l + ga);
            long gb = xb + (long)(j0 + wc * 32 + m * 16 + lr) * DD + oct * 8;
            b_h[m] = ld_bf8(X0h + gb);
            b_l[m] = ld_bf8(X0l + gb);
        }
#pragma unroll
        for (int m = 0; m < 2; ++m)
#pragma unroll
            for (int n = 0; n < 2; ++n) {
                acc[m][n] = mfma16(a_h[m], b_h[n], acc[m][n]);
                acc[m][n] = mfma16(a_h[m], b_l[n], acc[m][n]);
                acc[m][n] = mfma16(a_l[m], b_h[n], acc[m][n]);
            }
    }

    float* __restrict__ AEb = AE + (long)b * NN * NN;
#pragma unroll
    for (int m = 0; m < 2; ++m) {
        const int ib = i0 + wr * 32 + m * 16 + lg * 4;
#pragma unroll
        for (int n = 0; n < 2; ++n) {
            const int jc = j0 + wc * 32 + n * 16 + lr;
#pragma unroll
            for (int jj = 0; jj < 4; ++jj) {
                float v = fmaxf(acc[m][n][jj], 0.f);
                if (ib + jj == jc) v = 0.f;
                AEb[(long)(ib + jj) * NN + jc] = v;
            }
        }
    }
}

// ---------------------------------------------------------------------------
// LayerNorm over [N,D] + relu + mean/max pool. pre: fp32 col-major [64][512].
// h out: hi/lo bf16 planes row-major [512][64]. One 256-thr block per batch.
// ---------------------------------------------------------------------------
__global__ __launch_bounds__(256) void ln_pool(
    const float* __restrict__ pre, const float* __restrict__ gamma,
    const float* __restrict__ beta,
    unsigned short* __restrict__ hh, unsigned short* __restrict__ hl,
    float* __restrict__ zfeat, int zoff)
{
    const int b = blockIdx.x;
    const float* __restrict__ p = pre + (long)b * ND;
    const int t = threadIdx.x;

    float s = 0.f, s2 = 0.f;
    for (int i = t * 4; i < ND; i += 1024) {
        float4 v = *reinterpret_cast<const float4*>(p + i);
        s  += v.x + v.y + v.z + v.w;
        s2 += v.x * v.x + v.y * v.y + v.z * v.z + v.w * v.w;
    }
#pragma unroll
    for (int off = 32; off > 0; off >>= 1) {
        s  += __shfl_down(s, off, 64);
        s2 += __shfl_down(s2, off, 64);
    }
    __shared__ float red[8];
    if ((t & 63) == 0) { red[(t >> 6) * 2] = s; red[(t >> 6) * 2 + 1] = s2; }
    __syncthreads();
    __shared__ float mu_s, rstd_s;
    if (t == 0) {
        float ts  = red[0] + red[2] + red[4] + red[6];
        float ts2 = red[1] + red[3] + red[5] + red[7];
        float mu  = ts * (1.f / ND);
        float var = ts2 * (1.f / ND) - mu * mu;
        mu_s = mu; rstd_s = rsqrtf(var + 1e-5f);
    }
    __syncthreads();
    const float mu = mu_s, rstd = rstd_s;

    const int f4 = (t & 15) * 4, nt = t >> 4;
    float sum4[4] = {0.f, 0.f, 0.f, 0.f};
    float max4[4] = {0.f, 0.f, 0.f, 0.f};
    for (int n = nt; n < NN; n += 16) {
        float4 g4 = *reinterpret_cast<const float4*>(gamma + (long)n * DD + f4);
        float4 be = *reinterpret_cast<const float4*>(beta  + (long)n * DD + f4);
        float4 v;
        v.x = fmaxf((p[(long)(f4 + 0) * NN + n] - mu) * rstd * g4.x + be.x, 0.f);
        v.y = fmaxf((p[(long)(f4 + 1) * NN + n] - mu) * rstd * g4.y + be.y, 0.f);
        v.z = fmaxf((p[(long)(f4 + 2) * NN + n] - mu) * rstd * g4.z + be.z, 0.f);
        v.w = fmaxf((p[(long)(f4 + 3) * NN + n] - mu) * rstd * g4.w + be.w, 0.f);
        ushort4 h4, l4;
        cvt4(v, h4, l4);
        *reinterpret_cast<ushort4*>(hh + (long)b * ND + (long)n * DD + f4) = h4;
        *reinterpret_cast<ushort4*>(hl + (long)b * ND + (long)n * DD + f4) = l4;
        sum4[0] += v.x; sum4[1] += v.y; sum4[2] += v.z; sum4[3] += v.w;
        max4[0] = fmaxf(max4[0], v.x); max4[1] = fmaxf(max4[1], v.y);
        max4[2] = fmaxf(max4[2], v.z); max4[3] = fmaxf(max4[3], v.w);
    }
    __shared__ float rs[16][64], rm[16][64];
#pragma unroll
    for (int j = 0; j < 4; ++j) { rs[nt][f4 + j] = sum4[j]; rm[nt][f4 + j] = max4[j]; }
    __syncthreads();
    if (t < 64) {
        float ss = 0.f, mm = 0.f;
#pragma unroll
        for (int k = 0; k < 16; ++k) { ss += rs[k][t]; mm = fmaxf(mm, rm[k][t]); }
        zfeat[b * 256 + zoff + t]      = ss * (1.f / NN);
        zfeat[b * 256 + zoff + 64 + t] = mm;
    }
}

// ---------------------------------------------------------------------------
// W[z][kdim][64] fp32 -> hi/lo bf16 planes [z][64][kdim]
// ---------------------------------------------------------------------------
__global__ void transW_split(const float* __restrict__ W,
                             unsigned short* __restrict__ Wh,
                             unsigned short* __restrict__ Wl,
                             int kdim, int total)
{
    int o = blockIdx.x * 256 + threadIdx.x;
    if (o >= total) return;
    int per = 64 * kdim;
    int zz = o / per, r = o % per;
    int f = r / kdim, k = r % kdim;
    float x = W[((long)zz * kdim + k) * 64 + f];
    unsigned short hi = f2bf(x);
    Wh[o] = hi;
    Wl[o] = f2bf(x - bf2f(hi));
}

// ---------------------------------------------------------------------------
// Tiny MLP heads. One 64-thread block per batch row.
// ---------------------------------------------------------------------------
__global__ __launch_bounds__(64) void heads(
    const float* __restrict__ zfeat,
    const float* __restrict__ p1w, const float* __restrict__ p1b,
    const float* __restrict__ p2w, const float* __restrict__ p2b,
    const float* __restrict__ p3w, const float* __restrict__ p3b,
    const float* __restrict__ s1w, const float* __restrict__ s1b,
    const float* __restrict__ s2w, const float* __restrict__ s2b,
    const float* __restrict__ p4w, const float* __restrict__ p4b,
    float* __restrict__ outc, float* __restrict__ outs)
{
    const int b = blockIdx.x, t = threadIdx.x;
    __shared__ float zf[256], v1[64], v2[64], lg[2];
    for (int i = t; i < 256; i += 64) zf[i] = zfeat[b * 256 + i];
    __syncthreads();

    float a = p1b[t];
    for (int z = 0; z < 256; ++z) a = fmaf(zf[z], p1w[z * 64 + t], a);
    v1[t] = a >= 0.f ? a : 0.2f * a;
    __syncthreads();
    float a2 = p2b[t];
    for (int z = 0; z < 64; ++z) a2 = fmaf(v1[z], p2w[z * 64 + t], a2);
    v2[t] = a2 >= 0.f ? a2 : 0.2f * a2;
    __syncthreads();
    if (t < 4) {
        float a3 = p3b[t];
        for (int z = 0; z < 64; ++z) a3 = fmaf(v2[z], p3w[z * 4 + t], a3);
        outc[b * 4 + t] = 1.f / (1.f + expf(-a3));
    }
    __syncthreads();

    float c = s1b[t];
    for (int z = 0; z < 256; ++z) c = fmaf(zf[z], s1w[z * 64 + t], c);
    v1[t] = c >= 0.f ? c : 0.2f * c;
    __syncthreads();
    float c2 = s2b[t];
    for (int z = 0; z < 64; ++z) c2 = fmaf(v1[z], s2w[z * 64 + t], c2);
    v2[t] = c2 >= 0.f ? c2 : 0.2f * c2;
    __syncthreads();
    if (t < 2) {
        float d = p4b[t];
        for (int z = 0; z < 64; ++z) d = fmaf(v2[z], p4w[z * 2 + t], d);
        lg[t] = d;
    }
    __syncthreads();
    if (t < 2) {
        float m = fmaxf(lg[0], lg[1]);
        float lse = m + logf(expf(lg[0] - m) + expf(lg[1] - m));
        outs[b * 2 + t] = lg[t] - lse;
    }
}

// ---------------------------------------------------------------------------
// In-place Clenshaw in the 6 Z slots (hi/lo planes, col-major [b][64f][512n]):
//   g1: s4 <- 2A*s5 + s4      g2: s5 <- 2A*s4 - s5 + s3
//   g3: s4 <- 2A*s5 - s4 + s2 g4: s5 <- 2A*s4 - s5 + s1
//   g5: S  <-  A*s5 - s4 + s0 + bias
// Vm/Zt in-place reads are same-address-same-thread (safe); B never aliases out.
// ---------------------------------------------------------------------------
extern "C" void kernel_launch(void* const* d_in, const int* in_sizes, int n_in,
                              void* d_out, int out_size, void* d_ws, size_t ws_size,
                              hipStream_t stream)
{
    const float* A   = (const float*)d_in[0];
    const float* X   = (const float*)d_in[1];
    const float* W1  = (const float*)d_in[2];
    const float* b1v = (const float*)d_in[3];
    const float* W2  = (const float*)d_in[4];
    const float* b2v = (const float*)d_in[5];
    const float* W3  = (const float*)d_in[6];
    const float* b3v = (const float*)d_in[7];
    const float* g1  = (const float*)d_in[8];
    const float* bt1 = (const float*)d_in[9];
    const float* g2  = (const float*)d_in[10];
    const float* bt2 = (const float*)d_in[11];
    const float* p1w = (const float*)d_in[12];
    const float* p1b = (const float*)d_in[13];
    const float* p2w = (const float*)d_in[14];
    const float* p2b = (const float*)d_in[15];
    const float* p3w = (const float*)d_in[16];
    const float* p3b = (const float*)d_in[17];
    const float* s1w = (const float*)d_in[18];
    const float* s1b = (const float*)d_in[19];
    const float* s2w = (const float*)d_in[20];
    const float* s2b = (const float*)d_in[21];
    const float* p4w = (const float*)d_in[22];
    const float* p4b = (const float*)d_in[23];

    float* out = (float*)d_out;
    const long SLOTE = (long)BB * ND;                 // 2,097,152 elems per slot
    unsigned short* Zh = (unsigned short*)out;        // [6][64][64][512]
    unsigned short* Zl = Zh + 6 * SLOTE;
    float* Sbuf = out + 6 * SLOTE;                    // fp32 col-major (stage 1/2 out)
    float* outc  = out + (long)BB * NN * NN;
    float* outsc = outc + BB * 4;

    unsigned short* ws = (unsigned short*)d_ws;
    unsigned short* hh  = ws;                         // h hi, row-major [64][512][64]
    unsigned short* hl  = ws + SLOTE;
    unsigned short* X0h = hh;                         // alias: h dead before X0 written
    unsigned short* X0l = hl;
    unsigned short* w1h = ws + 2 * SLOTE;             // [6][64][512]
    unsigned short* w1l = w1h + 6 * NN * DD;
    unsigned short* w2h = w1l + 6 * NN * DD;          // [6][64][64]
    unsigned short* w2l = w2h + 6 * DD * DD;
    unsigned short* w3h = w2l + 6 * DD * DD;
    unsigned short* w3l = w3h + 6 * DD * DD;
    float* zfeat = (float*)(w3l + 6 * DD * DD);

    const dim3 blk(256);
    const long ABATCH = (long)NN * NN;
    const long USN = 0;

    transW_split<<<dim3((6 * NN * DD + 255) / 256), blk, 0, stream>>>(W1, w1h, w1l, NN, 6 * NN * DD);
    transW_split<<<dim3((6 * DD * DD + 255) / 256), blk, 0, stream>>>(W2, w2h, w2l, DD, 6 * DD * DD);
    transW_split<<<dim3((6 * DD * DD + 255) / 256), blk, 0, stream>>>(W3, w3h, w3l, DD, 6 * DD * DD);

    auto slotH = [&](int k) { return Zh + k * SLOTE; };
    auto slotL = [&](int k) { return Zl + k * SLOTE; };

    auto cheb = [&](const float* bias, int outf) {
        // g1: s4 = 2A*s5 + s4
        gemm_v3<0, false, true, false, 0><<<dim3(8, 64, 1), blk, 0, stream>>>(
            A, nullptr, nullptr, NN, ABATCH, slotH(5), slotL(5), (long)ND, USN,
            nullptr, nullptr, slotH(4), slotL(4), nullptr, 2.f, 0.f, NN,
            slotH(4), slotL(4), nullptr, USN);
        // g2: s5 = 2A*s4 - s5 + s3
        gemm_v3<0, true, true, false, 0><<<dim3(8, 64, 1), blk, 0, stream>>>(
            A, nullptr, nullptr, NN, ABATCH, slotH(4), slotL(4), (long)ND, USN,
            slotH(5), slotL(5), slotH(3), slotL(3), nullptr, 2.f, -1.f, NN,
            slotH(5), slotL(5), nullptr, USN);
        // g3: s4 = 2A*s5 - s4 + s2
        gemm_v3<0, true, true, false, 0><<<dim3(8, 64, 1), blk, 0, stream>>>(
            A, nullptr, nullptr, NN, ABATCH, slotH(5), slotL(5), (long)ND, USN,
            slotH(4), slotL(4), slotH(2), slotL(2), nullptr, 2.f, -1.f, NN,
            slotH(4), slotL(4), nullptr, USN);
        // g4: s5 = 2A*s4 - s5 + s1
        gemm_v3<0, true, true, false, 0><<<dim3(8, 64, 1), blk, 0, stream>>>(
            A, nullptr, nullptr, NN, ABATCH, slotH(4), slotL(4), (long)ND, USN,
            slotH(5), slotL(5), slotH(1), slotL(1), nullptr, 2.f, -1.f, NN,
            slotH(5), slotL(5), nullptr, USN);
        // g5: S = A*s5 - s4 + s0 + bias
        if (outf == 1)
            gemm_v3<0, true, true, true, 1><<<dim3(8, 64, 1), blk, 0, stream>>>(
                A, nullptr, nullptr, NN, ABATCH, slotH(5), slotL(5), (long)ND, USN,
                slotH(4), slotL(4), slotH(0), slotL(0), bias, 1.f, -1.f, NN,
                nullptr, nullptr, Sbuf, USN);
        else
            gemm_v3<0, true, true, true, 2><<<dim3(8, 64, 1), blk, 0, stream>>>(
                A, nullptr, nullptr, NN, ABATCH, slotH(5), slotL(5), (long)ND, USN,
                slotH(4), slotL(4), slotH(0), slotL(0), bias, 1.f, -1.f, NN,
                X0h, X0l, nullptr, USN);
    };

    // stage 1: Z_k = X @ W1[k] (X fp32, cvt-staged), then Clenshaw, LN, pool
    gemm_v3<0, false, false, false, 0><<<dim3(8, 64, 6), blk, 0, stream>>>(
        X, nullptr, nullptr, NN, ABATCH, w1h, w1l, 0L, (long)NN * DD,
        nullptr, nullptr, nullptr, nullptr, nullptr, 1.f, 0.f, NN,
        Zh, Zl, nullptr, SLOTE);
    cheb(b1v, 1);
    ln_pool<<<dim3(64), blk, 0, stream>>>(Sbuf, g1, bt1, hh, hl, zfeat, 0);

    // stage 2: Z_k = h @ W2[k] (h hi/lo register-direct, K=64)
    gemm_v3<1, false, false, false, 0><<<dim3(8, 64, 6), blk, 0, stream>>>(
        nullptr, hh, hl, DD, (long)ND, w2h, w2l, 0L, (long)DD * DD,
        nullptr, nullptr, nullptr, nullptr, nullptr, 1.f, 0.f, DD,
        Zh, Zl, nullptr, SLOTE);
    cheb(b2v, 1);
    ln_pool<<<dim3(64), blk, 0, stream>>>(Sbuf, g2, bt2, hh, hl, zfeat, 128);

    // stage 3: Z_k = h @ W3[k]; Clenshaw -> X0 hi/lo row-major (aliases h, h dead)
    gemm_v3<1, false, false, false, 0><<<dim3(8, 64, 6), blk, 0, stream>>>(
        nullptr, hh, hl, DD, (long)ND, w3h, w3l, 0L, (long)DD * DD,
        nullptr, nullptr, nullptr, nullptr, nullptr, 1.f, 0.f, DD,
        Zh, Zl, nullptr, SLOTE);
    cheb(b3v, 2);

    // AE = relu(X0 X0^T), zero diag
    outer_v3<<<dim3(8, 8, 64), blk, 0, stream>>>(X0h, X0l, out);

    // heads
    heads<<<dim3(64), dim3(64), 0, stream>>>(
        zfeat, p1w, p1b, p2w, p2b, p3w, p3b, s1w, s1b, s2w, s2b, p4w, p4b, outc, outsc);
}